// Round 3
// baseline (802.567 us; speedup 1.0000x reference)
//
#include <hip/hip_runtime.h>
#include <stdint.h>

typedef __attribute__((ext_vector_type(8))) short short8;
typedef __attribute__((ext_vector_type(4))) float floatx4;

#define T1 127
#define ENC 256
#define HD 256

// workspace offsets (bytes)
#define WHI_OFF   0u            // 1024*256 ushort = 524288
#define WLO_OFF   524288u
#define D0_OFF    1048576u      // 512*128 u64 = 524288  (epoch-tagged d words)
#define D1_OFF    1572864u
#define WEFF_OFF  2097152u      // 256 floats
#define YT_OFF    2099200u      // 512*128 fp32 = 262144
#define CTX_OFF   2361344u      // 512*256 fp32 = 524288
#define DT_OFF    2885632u      // 512*256 fp32 = 524288

__device__ __forceinline__ void split_bf16(float x, unsigned& hi, unsigned& lo) {
    unsigned u = __float_as_uint(x);
    hi = u >> 16;
    float hf = __uint_as_float(hi << 16);
    float r = x - hf;
    unsigned ur = __float_as_uint(r);
    lo = (ur + 0x7fffu + ((ur >> 16) & 1u)) >> 16;
}

// ---------------- k_prep: weight collapse + W_hh hi/lo split + init ----------------
__global__ __launch_bounds__(256) void k_prep(const float* __restrict__ W1,
                                              const float* __restrict__ W2,
                                              const float* __restrict__ W_hh,
                                              char* __restrict__ ws) {
    const int tid = threadIdx.x, bid = blockIdx.x;
    ushort* Whi = (ushort*)(ws + WHI_OFF);
    ushort* Wlo = (ushort*)(ws + WLO_OFF);
    // split W_hh (1024x256): each thread one float4
    {
        const int i4 = bid * 256 + tid;   // 0..65535
        float4 v = ((const float4*)W_hh)[i4];
        float vv[4] = {v.x, v.y, v.z, v.w};
        unsigned h[4], l[4];
        #pragma unroll
        for (int j = 0; j < 4; ++j) split_bf16(vv[j], h[j], l[j]);
        *(ushort4*)(Whi + i4 * 4) = make_ushort4((ushort)h[0], (ushort)h[1], (ushort)h[2], (ushort)h[3]);
        *(ushort4*)(Wlo + i4 * 4) = make_ushort4((ushort)l[0], (ushort)l[1], (ushort)l[2], (ushort)l[3]);
    }
    // zero d buffer 0: 512*128 u64 = 524288 B = 32768 uint4  (epoch 0, value 0)
    {
        const int idx = bid * 256 + tid;
        if (idx < 32768) ((uint4*)(ws + D0_OFF))[idx] = make_uint4(0, 0, 0, 0);
    }
    if (bid == 0) {
        // collapsed attention weight: weff[e] = sum_j W2[j] * W1[j,512+e]
        float acc = 0.f;
        for (int j = 0; j < 128; ++j)
            acc = fmaf(W2[j], W1[j * 768 + 512 + tid], acc);
        ((float*)(ws + WEFF_OFF))[tid] = acc;
    }
}

// ---------------- k_attn: scores -> softmax -> context -> y_tilde ----------------
__global__ __launch_bounds__(256) void k_attn(const float* __restrict__ X,
                                              const float* __restrict__ y_prev,
                                              const float* __restrict__ W_fc,
                                              const float* __restrict__ b_fc,
                                              char* __restrict__ ws) {
    __shared__ float s_lds[128];
    __shared__ float beta[128];
    __shared__ float red[256];
    const int b = blockIdx.x, tid = threadIdx.x;
    const int w = tid >> 6, lane = tid & 63;
    const float* Xb = X + (size_t)b * T1 * ENC;
    const float* weff = (const float*)(ws + WEFF_OFF);
    const float4 w4 = ((const float4*)weff)[lane];
    for (int i = 0; i < 32; ++i) {
        int t = w * 32 + i;
        if (t >= T1) break;
        float4 x4 = ((const float4*)(Xb + t * ENC))[lane];
        float a = x4.x * w4.x + x4.y * w4.y + x4.z * w4.z + x4.w * w4.w;
        for (int m = 32; m >= 1; m >>= 1) a += __shfl_xor(a, m, 64);
        if (lane == 0) s_lds[t] = a;
    }
    __syncthreads();
    if (w == 0) {
        float v0 = s_lds[lane];
        float v1 = (lane + 64 < T1) ? s_lds[lane + 64] : -1e30f;
        float mx = fmaxf(v0, v1);
        for (int m = 32; m >= 1; m >>= 1) mx = fmaxf(mx, __shfl_xor(mx, m, 64));
        float e0 = __expf(v0 - mx);
        float e1 = (lane + 64 < T1) ? __expf(v1 - mx) : 0.f;
        float s = e0 + e1;
        for (int m = 32; m >= 1; m >>= 1) s += __shfl_xor(s, m, 64);
        float inv = 1.f / s;
        beta[lane] = e0 * inv;
        if (lane + 64 < T1) beta[lane + 64] = e1 * inv;
    }
    __syncthreads();
    // context[b, tid]
    float acc = 0.f;
    for (int t = 0; t < T1; ++t) acc = fmaf(beta[t], Xb[t * ENC + tid], acc);
    ((float*)(ws + CTX_OFF))[b * ENC + tid] = acc;
    // u = W_fc[0:256] . context + b_fc
    red[tid] = acc * W_fc[tid];
    __syncthreads();
    for (int s = 128; s >= 1; s >>= 1) { if (tid < s) red[tid] += red[tid + s]; __syncthreads(); }
    const float u = red[0] + b_fc[0];
    const float wy = W_fc[256];
    if (tid < T1)
        ((float*)(ws + YT_OFF))[b * 128 + tid] = u + wy * y_prev[b * T1 + tid];
}

// ---------------- k_lstm: persistent sequential LSTM, epoch-in-data exchange ----------------
// 256 blocks: gi = bid>>3 (32 batch groups x 16 batches), hj = bid&7 (8 h-tiles x 32 h).
// W slice (32h x 4 gates x 256k, hi+lo bf16) resident in VGPRs.
// d exchanged as u64 words {hi1, lo1|e1, hi0, lo0|e0}: bf16 hi/lo planes of two cells
// with a 2-bit epoch in the lo-mantissa LSBs. One relaxed agent-scope atomic store
// publishes data+epoch; consumers poll the data words directly. No flags, no drains.
__global__ __launch_bounds__(256, 1) void k_lstm(const float* __restrict__ W_ih,
                                                 const float* __restrict__ b_ih,
                                                 const float* __restrict__ b_hh,
                                                 char* __restrict__ ws) {
    __shared__ __align__(16) ushort ldh[16 * 264];
    __shared__ __align__(16) ushort ldl[16 * 264];
    __shared__ float gbuf[16 * 132];

    const int tid = threadIdx.x, bid = blockIdx.x;
    const int gi = bid >> 3, hj = bid & 7;
    const int w = tid >> 6, lane = tid & 63;
    const int n16 = lane & 15, q = lane >> 4;

    const ushort* Whi = (const ushort*)(ws + WHI_OFF);
    const ushort* Wlo = (const ushort*)(ws + WLO_OFF);
    unsigned long long* Dbuf0 = (unsigned long long*)(ws + D0_OFF);
    unsigned long long* Dbuf1 = (unsigned long long*)(ws + D1_OFF);
    const float* yt = (const float*)(ws + YT_OFF);
    float* dT = (float*)(ws + DT_OFF);

    // resident W fragments: wave w owns N-tiles {2w, 2w+1}; row r = hloc*4 + g
    short8 bfh[2][8], bfl[2][8];
    #pragma unroll
    for (int j = 0; j < 2; ++j) {
        const int r = (2 * w + j) * 16 + n16;          // 0..127
        const int hloc = r >> 2, g = r & 3;
        const int R = g * 256 + hj * 32 + hloc;        // global gate row
        #pragma unroll
        for (int kt = 0; kt < 8; ++kt) {
            bfh[j][kt] = *(const short8*)(Whi + R * 256 + kt * 32 + q * 8);
            bfl[j][kt] = *(const short8*)(Wlo + R * 256 + kt * 32 + q * 8);
        }
    }

    // cell assignment: 16 batches x 32 h = 512 cells, 2 per thread
    const int b_loc = tid & 15, hpair = tid >> 4;      // hpair 0..15
    const int hloc0 = hpair * 2;
    const int bg = gi * 16 + b_loc;
    float wihr[2][4], bihr[2][4];
    #pragma unroll
    for (int jj = 0; jj < 2; ++jj)
        #pragma unroll
        for (int g = 0; g < 4; ++g) {
            const int row = g * HD + hj * 32 + hloc0 + jj;
            wihr[jj][g] = W_ih[row];
            bihr[jj][g] = b_ih[row] + b_hh[row];
        }
    float cc0 = 0.f, cc1 = 0.f;

    // poll/stage assignment: thread covers batch pb = tid>>4, hpair-octet hp8 = tid&15
    const int pb = tid >> 4, hp8 = tid & 15;
    const size_t pbase = (size_t)(gi * 16 + pb) * 128 + hp8 * 8;

    for (int t = 1; t <= T1; ++t) {
        // ---- poll the d_{t-1} slab directly; per-word 2-bit epoch check ----
        {
            unsigned long long* Dsrc = ((t - 1) & 1) ? Dbuf1 : Dbuf0;
            const unsigned e = (unsigned)(t - 1) & 3u;
            unsigned long long wv[8];
            #pragma unroll
            for (int i = 0; i < 8; ++i)
                wv[i] = __hip_atomic_load(&Dsrc[pbase + i], __ATOMIC_RELAXED,
                                          __HIP_MEMORY_SCOPE_AGENT);
            for (;;) {
                bool ok = true;
                #pragma unroll
                for (int i = 0; i < 8; ++i) {
                    unsigned ep = (unsigned)(wv[i] & 1ull) |
                                  (((unsigned)(wv[i] >> 32) & 1u) << 1);
                    ok &= (ep == e);
                }
                if (ok) break;
                #pragma unroll
                for (int i = 0; i < 8; ++i)
                    wv[i] = __hip_atomic_load(&Dsrc[pbase + i], __ATOMIC_RELAXED,
                                              __HIP_MEMORY_SCOPE_AGENT);
            }
            // decode into LDS hi/lo planes
            #pragma unroll
            for (int i = 0; i < 8; ++i) {
                const int hp = hp8 * 8 + i;
                unsigned h0 = (unsigned)(wv[i] >> 16) & 0xFFFFu;
                unsigned l0 = (unsigned)(wv[i] & 0xFFFEull);
                unsigned h1 = (unsigned)(wv[i] >> 48);
                unsigned l1 = (unsigned)(wv[i] >> 32) & 0xFFFEu;
                *(ushort2*)(ldh + pb * 264 + 2 * hp) = make_ushort2((ushort)h0, (ushort)h1);
                *(ushort2*)(ldl + pb * 264 + 2 * hp) = make_ushort2((ushort)l0, (ushort)l1);
            }
        }
        __syncthreads();
        // MFMA: gates[16b x 128r] = d[16x256] @ Wslice^T  (hi*hi + lo*hi + hi*lo)
        floatx4 acc0 = {0.f, 0.f, 0.f, 0.f}, acc1 = {0.f, 0.f, 0.f, 0.f};
        #pragma unroll
        for (int kt = 0; kt < 8; ++kt) {
            short8 ah = *(const short8*)(ldh + n16 * 264 + kt * 32 + q * 8);
            short8 al = *(const short8*)(ldl + n16 * 264 + kt * 32 + q * 8);
            acc0 = __builtin_amdgcn_mfma_f32_16x16x32_bf16(ah, bfh[0][kt], acc0, 0, 0, 0);
            acc0 = __builtin_amdgcn_mfma_f32_16x16x32_bf16(al, bfh[0][kt], acc0, 0, 0, 0);
            acc0 = __builtin_amdgcn_mfma_f32_16x16x32_bf16(ah, bfl[0][kt], acc0, 0, 0, 0);
            acc1 = __builtin_amdgcn_mfma_f32_16x16x32_bf16(ah, bfh[1][kt], acc1, 0, 0, 0);
            acc1 = __builtin_amdgcn_mfma_f32_16x16x32_bf16(al, bfh[1][kt], acc1, 0, 0, 0);
            acc1 = __builtin_amdgcn_mfma_f32_16x16x32_bf16(ah, bfl[1][kt], acc1, 0, 0, 0);
        }
        // scatter C-frags: row m = q*4+reg (batch), col = tile*16+n16 (gate row)
        #pragma unroll
        for (int reg = 0; reg < 4; ++reg) {
            gbuf[(q * 4 + reg) * 132 + (2 * w) * 16 + n16]     = acc0[reg];
            gbuf[(q * 4 + reg) * 132 + (2 * w + 1) * 16 + n16] = acc1[reg];
        }
        __syncthreads();
        // LSTM cell: 2 cells per thread
        const float ytv = yt[bg * 128 + (t - 1)];
        float dnew[2];
        #pragma unroll
        for (int jj = 0; jj < 2; ++jj) {
            const int base = b_loc * 132 + (hloc0 + jj) * 4;
            float pi = gbuf[base + 0] + ytv * wihr[jj][0] + bihr[jj][0];
            float pf = gbuf[base + 1] + ytv * wihr[jj][1] + bihr[jj][1];
            float pg = gbuf[base + 2] + ytv * wihr[jj][2] + bihr[jj][2];
            float po = gbuf[base + 3] + ytv * wihr[jj][3] + bihr[jj][3];
            float ig = 1.f / (1.f + __expf(-pi));
            float fg = 1.f / (1.f + __expf(-pf));
            float gg = tanhf(pg);
            float og = 1.f / (1.f + __expf(-po));
            float& c = jj ? cc1 : cc0;
            c = fg * c + ig * gg;
            dnew[jj] = og * tanhf(c);
        }
        if (t < T1) {
            // publish: one epoch-tagged u64 per thread, no drain, no flag
            const unsigned e = (unsigned)t & 3u;
            unsigned h0, l0, h1, l1;
            split_bf16(dnew[0], h0, l0);
            split_bf16(dnew[1], h1, l1);
            l0 = (l0 & 0xFFFEu) | (e & 1u);
            l1 = (l1 & 0xFFFEu) | ((e >> 1) & 1u);
            unsigned long long wv = ((unsigned long long)h1 << 48) |
                                    ((unsigned long long)l1 << 32) |
                                    ((unsigned long long)h0 << 16) |
                                    (unsigned long long)l0;
            unsigned long long* Ddst = (t & 1) ? Dbuf1 : Dbuf0;
            __hip_atomic_store(&Ddst[(size_t)bg * 128 + hj * 16 + hpair], wv,
                               __ATOMIC_RELAXED, __HIP_MEMORY_SCOPE_AGENT);
        } else {
            *(float2*)(dT + bg * 256 + hj * 32 + hloc0) = make_float2(dnew[0], dnew[1]);
        }
    }
}

// ---------------- k_final: y_pred = W_final . [dT, context] + b ----------------
__global__ __launch_bounds__(256) void k_final(const float* __restrict__ W_final,
                                               const float* __restrict__ b_final,
                                               float* __restrict__ out,
                                               char* __restrict__ ws) {
    __shared__ float red[256];
    const int b = blockIdx.x, tid = threadIdx.x;
    const float* dT = (const float*)(ws + DT_OFF);
    const float* ctx = (const float*)(ws + CTX_OFF);
    float v = W_final[tid] * dT[b * 256 + tid] + W_final[256 + tid] * ctx[b * 256 + tid];
    red[tid] = v;
    __syncthreads();
    for (int s = 128; s >= 1; s >>= 1) { if (tid < s) red[tid] += red[tid + s]; __syncthreads(); }
    if (tid == 0) out[b] = red[0] + b_final[0];
}

extern "C" void kernel_launch(void* const* d_in, const int* in_sizes, int n_in,
                              void* d_out, int out_size, void* d_ws, size_t ws_size,
                              hipStream_t stream) {
    const float* X      = (const float*)d_in[0];
    const float* y_prev = (const float*)d_in[1];
    const float* W1     = (const float*)d_in[2];
    const float* W2     = (const float*)d_in[4];
    const float* W_fc   = (const float*)d_in[6];
    const float* b_fc   = (const float*)d_in[7];
    const float* W_ih   = (const float*)d_in[8];
    const float* W_hh   = (const float*)d_in[9];
    const float* b_ih   = (const float*)d_in[10];
    const float* b_hh   = (const float*)d_in[11];
    const float* W_fin  = (const float*)d_in[12];
    const float* b_fin  = (const float*)d_in[13];
    char* ws = (char*)d_ws;

    hipLaunchKernelGGL(k_prep,  dim3(256), dim3(256), 0, stream, W1, W2, W_hh, ws);
    hipLaunchKernelGGL(k_attn,  dim3(512), dim3(256), 0, stream, X, y_prev, W_fc, b_fc, ws);
    hipLaunchKernelGGL(k_lstm,  dim3(256), dim3(256), 0, stream, W_ih, b_ih, b_hh, ws);
    hipLaunchKernelGGL(k_final, dim3(512), dim3(256), 0, stream, W_fin, b_fin, (float*)d_out, ws);
}

// Round 5
// 655.228 us; speedup vs baseline: 1.2249x; 1.2249x over previous
//
#include <hip/hip_runtime.h>
#include <stdint.h>

typedef __attribute__((ext_vector_type(8))) short short8;
typedef __attribute__((ext_vector_type(8))) unsigned short ushort8_t;
typedef __attribute__((ext_vector_type(4))) float floatx4;

#define T1 127
#define ENC 256
#define HD 256

// workspace offsets (bytes)
#define WHI_OFF   0u            // 1024*256 ushort = 524288
#define WLO_OFF   524288u
#define D0_OFF    1048576u      // 512*128 u64 = 524288  (epoch-tagged d words)
#define D1_OFF    1572864u
#define WEFF_OFF  2097152u      // 256 floats
#define YT_OFF    2099200u      // 512*128 fp32 = 262144
#define CTX_OFF   2361344u      // 512*256 fp32 = 524288
#define DT_OFF    2885632u      // 512*256 fp32 = 524288

__device__ __forceinline__ void split_bf16(float x, unsigned& hi, unsigned& lo) {
    unsigned u = __float_as_uint(x);
    hi = u >> 16;
    float hf = __uint_as_float(hi << 16);
    float r = x - hf;
    unsigned ur = __float_as_uint(r);
    lo = (ur + 0x7fffu + ((ur >> 16) & 1u)) >> 16;
}

__device__ __forceinline__ float sigm_f(float x) { return 1.f / (1.f + __expf(-x)); }
__device__ __forceinline__ float tanh_f(float x) {
    x = fminf(9.f, fmaxf(-9.f, x));
    float e = __expf(2.f * x);
    return (e - 1.f) / (e + 1.f);
}

// ---------------- k_prep: weight collapse + W_hh hi/lo split + init ----------------
__global__ __launch_bounds__(256) void k_prep(const float* __restrict__ W1,
                                              const float* __restrict__ W2,
                                              const float* __restrict__ W_hh,
                                              char* __restrict__ ws) {
    const int tid = threadIdx.x, bid = blockIdx.x;
    ushort* Whi = (ushort*)(ws + WHI_OFF);
    ushort* Wlo = (ushort*)(ws + WLO_OFF);
    // split W_hh (1024x256): each thread one float4
    {
        const int i4 = bid * 256 + tid;   // 0..65535
        float4 v = ((const float4*)W_hh)[i4];
        float vv[4] = {v.x, v.y, v.z, v.w};
        unsigned h[4], l[4];
        #pragma unroll
        for (int j = 0; j < 4; ++j) split_bf16(vv[j], h[j], l[j]);
        *(ushort4*)(Whi + i4 * 4) = make_ushort4((ushort)h[0], (ushort)h[1], (ushort)h[2], (ushort)h[3]);
        *(ushort4*)(Wlo + i4 * 4) = make_ushort4((ushort)l[0], (ushort)l[1], (ushort)l[2], (ushort)l[3]);
    }
    // zero d buffer 0: 512*128 u64 = 524288 B = 32768 uint4  (epoch 0, value 0)
    {
        const int idx = bid * 256 + tid;
        if (idx < 32768) ((uint4*)(ws + D0_OFF))[idx] = make_uint4(0, 0, 0, 0);
    }
    if (bid == 0) {
        // collapsed attention weight: weff[e] = sum_j W2[j] * W1[j,512+e]
        float acc = 0.f;
        for (int j = 0; j < 128; ++j)
            acc = fmaf(W2[j], W1[j * 768 + 512 + tid], acc);
        ((float*)(ws + WEFF_OFF))[tid] = acc;
    }
}

// ---------------- k_attn: scores -> softmax -> context -> y_tilde ----------------
__global__ __launch_bounds__(256) void k_attn(const float* __restrict__ X,
                                              const float* __restrict__ y_prev,
                                              const float* __restrict__ W_fc,
                                              const float* __restrict__ b_fc,
                                              char* __restrict__ ws) {
    __shared__ float s_lds[128];
    __shared__ float beta[128];
    __shared__ float red[256];
    const int b = blockIdx.x, tid = threadIdx.x;
    const int w = tid >> 6, lane = tid & 63;
    const float* Xb = X + (size_t)b * T1 * ENC;
    const float* weff = (const float*)(ws + WEFF_OFF);
    const float4 w4 = ((const float4*)weff)[lane];
    for (int i = 0; i < 32; ++i) {
        int t = w * 32 + i;
        if (t >= T1) break;
        float4 x4 = ((const float4*)(Xb + t * ENC))[lane];
        float a = x4.x * w4.x + x4.y * w4.y + x4.z * w4.z + x4.w * w4.w;
        for (int m = 32; m >= 1; m >>= 1) a += __shfl_xor(a, m, 64);
        if (lane == 0) s_lds[t] = a;
    }
    __syncthreads();
    if (w == 0) {
        float v0 = s_lds[lane];
        float v1 = (lane + 64 < T1) ? s_lds[lane + 64] : -1e30f;
        float mx = fmaxf(v0, v1);
        for (int m = 32; m >= 1; m >>= 1) mx = fmaxf(mx, __shfl_xor(mx, m, 64));
        float e0 = __expf(v0 - mx);
        float e1 = (lane + 64 < T1) ? __expf(v1 - mx) : 0.f;
        float s = e0 + e1;
        for (int m = 32; m >= 1; m >>= 1) s += __shfl_xor(s, m, 64);
        float inv = 1.f / s;
        beta[lane] = e0 * inv;
        if (lane + 64 < T1) beta[lane + 64] = e1 * inv;
    }
    __syncthreads();
    // context[b, tid]
    float acc = 0.f;
    for (int t = 0; t < T1; ++t) acc = fmaf(beta[t], Xb[t * ENC + tid], acc);
    ((float*)(ws + CTX_OFF))[b * ENC + tid] = acc;
    // u = W_fc[0:256] . context + b_fc
    red[tid] = acc * W_fc[tid];
    __syncthreads();
    for (int s = 128; s >= 1; s >>= 1) { if (tid < s) red[tid] += red[tid + s]; __syncthreads(); }
    const float u = red[0] + b_fc[0];
    const float wy = W_fc[256];
    if (tid < T1)
        ((float*)(ws + YT_OFF))[b * 128 + tid] = u + wy * y_prev[b * T1 + tid];
}

// ---------------- k_lstm: persistent sequential LSTM, epoch-in-data exchange ----------------
// 256 blocks: gi = bid>>3 (32 batch groups x 16 batches), hj = bid&7 (8 h-tiles x 32 h).
// W slice (32h x 4 gates x 256k, hi+lo bf16) resident in VGPRs.
// d exchanged as u64 words {hi1, lo1|e1, hi0, lo0|e0}. Consumers poll data words
// directly (stale-only reload + s_sleep backoff). Own h-slice never round-trips
// through global: producers write it straight into next step's LDS slab.
__global__ __launch_bounds__(256, 1) void k_lstm(const float* __restrict__ W_ih,
                                                 const float* __restrict__ b_ih,
                                                 const float* __restrict__ b_hh,
                                                 char* __restrict__ ws) {
    __shared__ __align__(16) ushort ldh[16 * 264];
    __shared__ __align__(16) ushort ldl[16 * 264];
    __shared__ float gbuf[16 * 132];

    const int tid = threadIdx.x, bid = blockIdx.x;
    const int gi = bid >> 3, hj = bid & 7;
    const int w = tid >> 6, lane = tid & 63;
    const int n16 = lane & 15, q = lane >> 4;

    const ushort* Whi = (const ushort*)(ws + WHI_OFF);
    const ushort* Wlo = (const ushort*)(ws + WLO_OFF);
    unsigned long long* Dbuf0 = (unsigned long long*)(ws + D0_OFF);
    unsigned long long* Dbuf1 = (unsigned long long*)(ws + D1_OFF);
    const float* yt = (const float*)(ws + YT_OFF);
    float* dT = (float*)(ws + DT_OFF);

    // resident W fragments: wave w owns N-tiles {2w, 2w+1}; row r = hloc*4 + g
    short8 bfh[2][8], bfl[2][8];
    #pragma unroll
    for (int j = 0; j < 2; ++j) {
        const int r = (2 * w + j) * 16 + n16;          // 0..127
        const int hloc = r >> 2, g = r & 3;
        const int R = g * 256 + hj * 32 + hloc;        // global gate row
        #pragma unroll
        for (int kt = 0; kt < 8; ++kt) {
            bfh[j][kt] = *(const short8*)(Whi + R * 256 + kt * 32 + q * 8);
            bfl[j][kt] = *(const short8*)(Wlo + R * 256 + kt * 32 + q * 8);
        }
    }

    // cell assignment: 16 batches x 32 h = 512 cells, 2 per thread
    const int b_loc = tid & 15, hpair = tid >> 4;      // hpair 0..15
    const int hloc0 = hpair * 2;
    const int bg = gi * 16 + b_loc;
    float wihr[2][4], bihr[2][4];
    #pragma unroll
    for (int jj = 0; jj < 2; ++jj)
        #pragma unroll
        for (int g = 0; g < 4; ++g) {
            const int row = g * HD + hj * 32 + hloc0 + jj;
            wihr[jj][g] = W_ih[row];
            bihr[jj][g] = b_ih[row] + b_hh[row];
        }
    float cc0 = 0.f, cc1 = 0.f;

    // poll/stage assignment: thread covers batch pb = tid>>4, hp8 = tid&15
    // words k = hp8*8 .. hp8*8+7 (cells h = 2k, 2k+1); origin block = hp8>>1
    const int pb = tid >> 4, hp8 = tid & 15;
    const bool own = ((hp8 >> 1) == hj);
    const size_t pbase = (size_t)(gi * 16 + pb) * 128 + hp8 * 8;

    // pre-zero this thread's full 16-ushort slab segment (d0 = 0) in BOTH planes.
    // (R4 bug: only the first 8 ushorts were zeroed -> own-slice garbage -> NaN.)
    {
        ushort8_t z = {0, 0, 0, 0, 0, 0, 0, 0};
        *(ushort8_t*)(ldh + pb * 264 + hp8 * 16)     = z;
        *(ushort8_t*)(ldh + pb * 264 + hp8 * 16 + 8) = z;
        *(ushort8_t*)(ldl + pb * 264 + hp8 * 16)     = z;
        *(ushort8_t*)(ldl + pb * 264 + hp8 * 16 + 8) = z;
    }

    for (int t = 1; t <= T1; ++t) {
        const float ytv = yt[bg * 128 + (t - 1)];   // prefetch, independent of d
        // ---- poll d_{t-1}: stale-only reload with backoff; skip own slice ----
        if (!own) {
            unsigned long long* Dsrc = ((t - 1) & 1) ? Dbuf1 : Dbuf0;
            const unsigned e = (unsigned)(t - 1) & 3u;
            unsigned long long wv[8];
            #pragma unroll
            for (int i = 0; i < 8; ++i)
                wv[i] = __hip_atomic_load(&Dsrc[pbase + i], __ATOMIC_RELAXED,
                                          __HIP_MEMORY_SCOPE_AGENT);
            unsigned stale = 0xFFu;
            for (;;) {
                unsigned ns = 0;
                #pragma unroll
                for (int i = 0; i < 8; ++i)
                    if (stale & (1u << i)) {
                        unsigned ep = (unsigned)(wv[i] & 1ull) |
                                      (((unsigned)(wv[i] >> 32) & 1u) << 1);
                        if (ep != e) ns |= 1u << i;
                    }
                if (!ns) break;
                __builtin_amdgcn_s_sleep(1);
                #pragma unroll
                for (int i = 0; i < 8; ++i)
                    if (ns & (1u << i))
                        wv[i] = __hip_atomic_load(&Dsrc[pbase + i], __ATOMIC_RELAXED,
                                                  __HIP_MEMORY_SCOPE_AGENT);
                stale = ns;
            }
            // decode: 16 hi + 16 lo ushorts -> one b128 store per plane
            ushort hv[16], lv[16];
            #pragma unroll
            for (int i = 0; i < 8; ++i) {
                hv[2 * i]     = (ushort)((wv[i] >> 16) & 0xFFFFull);
                hv[2 * i + 1] = (ushort)(wv[i] >> 48);
                lv[2 * i]     = (ushort)(wv[i] & 0xFFFEull);
                lv[2 * i + 1] = (ushort)((wv[i] >> 32) & 0xFFFEull);
            }
            ushort8_t H0, L0;
            #pragma unroll
            for (int i = 0; i < 8; ++i) { H0[i] = hv[i]; L0[i] = lv[i]; }
            ushort8_t H1, L1;
            #pragma unroll
            for (int i = 0; i < 8; ++i) { H1[i] = hv[8 + i]; L1[i] = lv[8 + i]; }
            *(ushort8_t*)(ldh + pb * 264 + hp8 * 16)     = H0;
            *(ushort8_t*)(ldh + pb * 264 + hp8 * 16 + 8) = H1;
            *(ushort8_t*)(ldl + pb * 264 + hp8 * 16)     = L0;
            *(ushort8_t*)(ldl + pb * 264 + hp8 * 16 + 8) = L1;
        }
        __syncthreads();
        // MFMA: gates[16b x 128r] = d[16x256] @ Wslice^T  (hi*hi + lo*hi + hi*lo)
        floatx4 acc0 = {0.f, 0.f, 0.f, 0.f}, acc1 = {0.f, 0.f, 0.f, 0.f};
        #pragma unroll
        for (int kt = 0; kt < 8; ++kt) {
            short8 ah = *(const short8*)(ldh + n16 * 264 + kt * 32 + q * 8);
            short8 al = *(const short8*)(ldl + n16 * 264 + kt * 32 + q * 8);
            acc0 = __builtin_amdgcn_mfma_f32_16x16x32_bf16(ah, bfh[0][kt], acc0, 0, 0, 0);
            acc0 = __builtin_amdgcn_mfma_f32_16x16x32_bf16(al, bfh[0][kt], acc0, 0, 0, 0);
            acc0 = __builtin_amdgcn_mfma_f32_16x16x32_bf16(ah, bfl[0][kt], acc0, 0, 0, 0);
            acc1 = __builtin_amdgcn_mfma_f32_16x16x32_bf16(ah, bfh[1][kt], acc1, 0, 0, 0);
            acc1 = __builtin_amdgcn_mfma_f32_16x16x32_bf16(al, bfh[1][kt], acc1, 0, 0, 0);
            acc1 = __builtin_amdgcn_mfma_f32_16x16x32_bf16(ah, bfl[1][kt], acc1, 0, 0, 0);
        }
        // scatter C-frags: row m = q*4+reg (batch), col = tile*16+n16 (gate row)
        #pragma unroll
        for (int reg = 0; reg < 4; ++reg) {
            gbuf[(q * 4 + reg) * 132 + (2 * w) * 16 + n16]     = acc0[reg];
            gbuf[(q * 4 + reg) * 132 + (2 * w + 1) * 16 + n16] = acc1[reg];
        }
        __syncthreads();
        // LSTM cell: 2 cells per thread
        float dnew[2];
        #pragma unroll
        for (int jj = 0; jj < 2; ++jj) {
            const int base = b_loc * 132 + (hloc0 + jj) * 4;
            float pi = gbuf[base + 0] + ytv * wihr[jj][0] + bihr[jj][0];
            float pf = gbuf[base + 1] + ytv * wihr[jj][1] + bihr[jj][1];
            float pg = gbuf[base + 2] + ytv * wihr[jj][2] + bihr[jj][2];
            float po = gbuf[base + 3] + ytv * wihr[jj][3] + bihr[jj][3];
            float ig = sigm_f(pi), fg = sigm_f(pf), og = sigm_f(po);
            float gg = tanh_f(pg);
            float& c = jj ? cc1 : cc0;
            c = fg * c + ig * gg;
            dnew[jj] = og * tanh_f(c);
        }
        if (t < T1) {
            const unsigned e = (unsigned)t & 3u;
            unsigned h0, l0, h1, l1;
            split_bf16(dnew[0], h0, l0);
            split_bf16(dnew[1], h1, l1);
            l0 = (l0 & 0xFFFEu) | (e & 1u);
            l1 = (l1 & 0xFFFEu) | ((e >> 1) & 1u);
            // own slice -> directly into next step's LDS slab (safe: past this
            // step's MFMA reads; ordered vs next step's reads by decode barrier)
            *(ushort2*)(ldh + b_loc * 264 + hj * 32 + hloc0) =
                make_ushort2((ushort)h0, (ushort)h1);
            *(ushort2*)(ldl + b_loc * 264 + hj * 32 + hloc0) =
                make_ushort2((ushort)(l0 & 0xFFFEu), (ushort)(l1 & 0xFFFEu));
            // publish for the other 7 blocks of the group
            unsigned long long wv = ((unsigned long long)h1 << 48) |
                                    ((unsigned long long)l1 << 32) |
                                    ((unsigned long long)h0 << 16) |
                                    (unsigned long long)l0;
            unsigned long long* Ddst = (t & 1) ? Dbuf1 : Dbuf0;
            __hip_atomic_store(&Ddst[(size_t)bg * 128 + hj * 16 + hpair], wv,
                               __ATOMIC_RELAXED, __HIP_MEMORY_SCOPE_AGENT);
        } else {
            *(float2*)(dT + bg * 256 + hj * 32 + hloc0) = make_float2(dnew[0], dnew[1]);
        }
    }
}

// ---------------- k_final: y_pred = W_final . [dT, context] + b ----------------
__global__ __launch_bounds__(256) void k_final(const float* __restrict__ W_final,
                                               const float* __restrict__ b_final,
                                               float* __restrict__ out,
                                               char* __restrict__ ws) {
    __shared__ float red[256];
    const int b = blockIdx.x, tid = threadIdx.x;
    const float* dT = (const float*)(ws + DT_OFF);
    const float* ctx = (const float*)(ws + CTX_OFF);
    float v = W_final[tid] * dT[b * 256 + tid] + W_final[256 + tid] * ctx[b * 256 + tid];
    red[tid] = v;
    __syncthreads();
    for (int s = 128; s >= 1; s >>= 1) { if (tid < s) red[tid] += red[tid + s]; __syncthreads(); }
    if (tid == 0) out[b] = red[0] + b_final[0];
}

extern "C" void kernel_launch(void* const* d_in, const int* in_sizes, int n_in,
                              void* d_out, int out_size, void* d_ws, size_t ws_size,
                              hipStream_t stream) {
    const float* X      = (const float*)d_in[0];
    const float* y_prev = (const float*)d_in[1];
    const float* W1     = (const float*)d_in[2];
    const float* W2     = (const float*)d_in[4];
    const float* W_fc   = (const float*)d_in[6];
    const float* b_fc   = (const float*)d_in[7];
    const float* W_ih   = (const float*)d_in[8];
    const float* W_hh   = (const float*)d_in[9];
    const float* b_ih   = (const float*)d_in[10];
    const float* b_hh   = (const float*)d_in[11];
    const float* W_fin  = (const float*)d_in[12];
    const float* b_fin  = (const float*)d_in[13];
    char* ws = (char*)d_ws;

    hipLaunchKernelGGL(k_prep,  dim3(256), dim3(256), 0, stream, W1, W2, W_hh, ws);
    hipLaunchKernelGGL(k_attn,  dim3(512), dim3(256), 0, stream, X, y_prev, W_fc, b_fc, ws);
    hipLaunchKernelGGL(k_lstm,  dim3(256), dim3(256), 0, stream, W_ih, b_ih, b_hh, ws);
    hipLaunchKernelGGL(k_final, dim3(512), dim3(256), 0, stream, W_fin, b_fin, (float*)d_out, ws);
}